// Round 4
// baseline (1524.550 us; speedup 1.0000x reference)
//
#include <hip/hip_runtime.h>
#include <math.h>

#define NB 64
#define S_ 432
#define D_ 512
#define C_ 128
#define HB 32   // batches per chunk for the per-batch (cov->NS->attn) pipeline

typedef unsigned short ushort_t;
typedef unsigned int uint_t;
typedef __attribute__((ext_vector_type(8))) short short8;
typedef __attribute__((ext_vector_type(4))) float f32x4;

// ---- bf16 helpers (RNE) ----
__device__ inline ushort_t f2bf(float v) {
    uint_t x = __float_as_uint(v);
    x += 0x7fffu + ((x >> 16) & 1u);
    return (ushort_t)(x >> 16);
}
__device__ inline float bf2f(ushort_t b) { return __uint_as_float(((uint_t)b) << 16); }
__device__ inline void split2(float v, ushort_t& h, ushort_t& l) {
    h = f2bf(v);
    l = f2bf(v - bf2f(h));
}

// relu on packed bf16 pairs: x>0 iff hi>0 (RNE never crosses zero); lo follows hi's mask
__device__ inline void relu4(uint4& h, uint4& l) {
    uint_t* hp = (uint_t*)&h; uint_t* lp = (uint_t*)&l;
    #pragma unroll
    for (int i = 0; i < 4; ++i) {
        uint_t hv = hp[i];
        uint_t mlo = ((hv & 0x8000u) == 0u && (hv & 0xffffu) != 0u) ? 0xffffu : 0u;
        uint_t mhi = ((hv & 0x80000000u) == 0u && (hv & 0xffff0000u) != 0u) ? 0xffff0000u : 0u;
        uint_t m = mlo | mhi;
        hp[i] = hv & m; lp[i] = lp[i] & m;
    }
}

// ---- elementwise fp32 -> (hi,lo) bf16 split ----
__global__ __launch_bounds__(256)
void split_k(const float* __restrict__ src, ushort_t* __restrict__ dh,
             ushort_t* __restrict__ dl, long n4) {
    long i = (long)blockIdx.x * 256 + threadIdx.x;
    long stride = (long)gridDim.x * 256;
    for (; i < n4; i += stride) {
        float4 v = *(const float4*)&src[i * 4];
        ushort_t h0,l0,h1,l1,h2,l2,h3,l3;
        split2(v.x,h0,l0); split2(v.y,h1,l1); split2(v.z,h2,l2); split2(v.w,h3,l3);
        uint2 ph, pl;
        ph.x = (uint_t)h0 | ((uint_t)h1 << 16); ph.y = (uint_t)h2 | ((uint_t)h3 << 16);
        pl.x = (uint_t)l0 | ((uint_t)l1 << 16); pl.y = (uint_t)l2 | ((uint_t)l3 << 16);
        *(uint2*)&dh[i * 4] = ph; *(uint2*)&dl[i * 4] = pl;
    }
}

// ---------------------------------------------------------------------------
// Split-bf16 MFMA GEMM: C[m,n] = epi( sum_k A[m,k] * Bg[n,k] )
// A as (M,K) hi/lo bf16 k-contig; Bg as (N,K) hi/lo k-contig (B^T stored, or B
// itself when symmetric -- all Newton-Schulz operands are).
// acc += Ah*Bh + Ah*Bl + Al*Bh  (3 MFMAs/frag-pair; dropped l*l term ~2^-18 rel).
// Tile 128x128, 4 waves (2x2), each wave 64x64 = 4x4 frags of 16x16x32 bf16.
// C/D frag map (m89-verified): col = lane&15, row = (lane>>4)*4 + reg.
// F: 0 none | 1 0.5*(3I-acc) | 2 cov dual-output | 4 *e0[n]+e1[n]
//  | 5 *sqrt(trc/128)/16 | 6 +e0[m] (row bias)
// WS: write hi/lo splits to Ch/Cl. WF: write fp32 to Cf.
// F==2: Ah=(acc-128*mu_m*mu_n)/trc -> Ch/Cl ; ZY0=0.5(3I-Ah) -> C2h/C2l.
// Grid edge: m0=min(bx*128, M-128) -> overlapped blocks write identical bits.
// ---------------------------------------------------------------------------
template<int F, bool RELU, bool WS, bool WF>
__global__ __launch_bounds__(256)
void gemm_bf(const ushort_t* __restrict__ Agh, const ushort_t* __restrict__ Agl,
             const ushort_t* __restrict__ Bgh, const ushort_t* __restrict__ Bgl,
             ushort_t* __restrict__ Ch, ushort_t* __restrict__ Cl,
             ushort_t* __restrict__ C2h, ushort_t* __restrict__ C2l,
             float* __restrict__ Cf,
             int M, int N, int K, int lda, int ldb, int ldc,
             long sA, long sB, long sC,
             const float* __restrict__ e0, const float* __restrict__ e1,
             const float* __restrict__ trc, const float* __restrict__ mu)
{
    __shared__ __align__(16) ushort_t lds[4][128][40];  // Ah,Al,Bh,Bl tiles; 40 KB

    const int zb = blockIdx.z;
    const int tid = threadIdx.x;
    const int m0 = min((int)blockIdx.x * 128, M - 128);
    const int n0 = min((int)blockIdx.y * 128, N - 128);

    const ushort_t* gAh = Agh + (long)zb * sA;
    const ushort_t* gAl = Agl + (long)zb * sA;
    const ushort_t* gBh = Bgh + (long)zb * sB;
    const ushort_t* gBl = Bgl + (long)zb * sB;

    f32x4 acc[4][4];
    #pragma unroll
    for (int i = 0; i < 4; ++i)
        #pragma unroll
        for (int j = 0; j < 4; ++j)
            acc[i][j] = (f32x4){0.f, 0.f, 0.f, 0.f};

    const int srow = tid >> 2;        // 0..63
    const int sq   = (tid & 3) * 8;   // k offset (ushorts): 0,8,16,24
    const int wv = tid >> 6, wr = wv >> 1, wc = wv & 1;
    const int ln = tid & 63, lm = ln & 15, kg = ln >> 4;

    for (int k0 = 0; k0 < K; k0 += 32) {
        const bool kok = (k0 + sq) < K;   // K%16==0, sq%8==0 -> full 8 valid if true
        #pragma unroll
        for (int ps = 0; ps < 2; ++ps) {
            int r = srow + ps * 64;
            uint4 z4; z4.x = z4.y = z4.z = z4.w = 0u;
            uint4 vh = z4, vl = z4, wh = z4, wl = z4;
            if (kok) {
                long ao = (long)(m0 + r) * lda + k0 + sq;
                long bo = (long)(n0 + r) * ldb + k0 + sq;
                vh = *(const uint4*)(gAh + ao);
                vl = *(const uint4*)(gAl + ao);
                wh = *(const uint4*)(gBh + bo);
                wl = *(const uint4*)(gBl + bo);
            }
            if (RELU) relu4(vh, vl);
            *(uint4*)&lds[0][r][sq] = vh;
            *(uint4*)&lds[1][r][sq] = vl;
            *(uint4*)&lds[2][r][sq] = wh;
            *(uint4*)&lds[3][r][sq] = wl;
        }
        __syncthreads();
        short8 ah[4], al[4], bh[4], bl[4];
        #pragma unroll
        for (int fm = 0; fm < 4; ++fm) {
            ah[fm] = *(const short8*)&lds[0][wr*64 + fm*16 + lm][kg*8];
            al[fm] = *(const short8*)&lds[1][wr*64 + fm*16 + lm][kg*8];
        }
        #pragma unroll
        for (int fn = 0; fn < 4; ++fn) {
            bh[fn] = *(const short8*)&lds[2][wc*64 + fn*16 + lm][kg*8];
            bl[fn] = *(const short8*)&lds[3][wc*64 + fn*16 + lm][kg*8];
        }
        #pragma unroll
        for (int fm = 0; fm < 4; ++fm)
            #pragma unroll
            for (int fn = 0; fn < 4; ++fn) {
                acc[fm][fn] = __builtin_amdgcn_mfma_f32_16x16x32_bf16(ah[fm], bh[fn], acc[fm][fn], 0, 0, 0);
                acc[fm][fn] = __builtin_amdgcn_mfma_f32_16x16x32_bf16(ah[fm], bl[fn], acc[fm][fn], 0, 0, 0);
                acc[fm][fn] = __builtin_amdgcn_mfma_f32_16x16x32_bf16(al[fm], bh[fn], acc[fm][fn], 0, 0, 0);
            }
        __syncthreads();
    }

    // ---- epilogue ----
    const int rg = kg * 4;
    float fscale = 1.f, invtr = 1.f;
    if (F == 5) fscale = sqrtf(trc[zb] * (1.0f / 128.0f)) * 0.0625f;
    if (F == 2) invtr = 1.0f / trc[zb];

    #pragma unroll
    for (int fm = 0; fm < 4; ++fm) {
        #pragma unroll
        for (int r = 0; r < 4; ++r) {
            int gm = m0 + wr*64 + fm*16 + rg + r;
            float mum = 0.f;
            if (F == 2) mum = mu[(long)zb * S_ + gm];
            #pragma unroll
            for (int fn = 0; fn < 4; ++fn) {
                int gn = n0 + wc*64 + fn*16 + lm;
                float v = acc[fm][fn][r];
                long o = (long)zb * sC + (long)gm * ldc + gn;
                if (F == 2) {
                    float ahv = (v - 128.0f * mum * mu[(long)zb * S_ + gn]) * invtr;
                    ushort_t h, l; split2(ahv, h, l);
                    Ch[o] = h; Cl[o] = l;
                    float z0 = ((gm == gn) ? 1.5f : 0.0f) - 0.5f * ahv;
                    split2(z0, h, l);
                    C2h[o] = h; C2l[o] = l;
                } else {
                    if (F == 1)      v = ((gm == gn) ? 1.5f : 0.0f) - 0.5f * v;
                    else if (F == 4) v = v * e0[gn] + e1[gn];
                    else if (F == 5) v *= fscale;
                    else if (F == 6) v += e0[gm];
                    if (WF) Cf[o] = v;
                    if (WS) { ushort_t h, l; split2(v, h, l); Ch[o] = h; Cl[o] = l; }
                }
            }
        }
    }
}

// ---- BN fold: feat = acc*sc[c] + sh[c] ----
__global__ void bnfold_k(const float* __restrict__ bc, const float* __restrict__ gamma,
                         const float* __restrict__ beta, const float* __restrict__ mean,
                         const float* __restrict__ var, float* __restrict__ sc,
                         float* __restrict__ sh)
{
    int c = threadIdx.x;
    float s = gamma[c] / sqrtf(var[c] + 1e-5f);
    sc[c] = s;
    sh[c] = beta[c] + (bc[c] - mean[c]) * s;
}

// ---- per-row channel mean + trace contribution (one wave per feat row) ----
__global__ __launch_bounds__(256)
void mu_rowq_bf(const ushort_t* __restrict__ fh, const ushort_t* __restrict__ fl,
                float* __restrict__ mu, float* __restrict__ rowq)
{
    int row  = blockIdx.x * 4 + (threadIdx.x >> 6);
    int lane = threadIdx.x & 63;
    uint_t h = *(const uint_t*)&fh[(long)row * C_ + lane * 2];
    uint_t l = *(const uint_t*)&fl[(long)row * C_ + lane * 2];
    float f0 = bf2f((ushort_t)(h & 0xffffu)) + bf2f((ushort_t)(l & 0xffffu));
    float f1 = bf2f((ushort_t)(h >> 16)) + bf2f((ushort_t)(l >> 16));
    float sum = f0 + f1;
    float sq  = f0 * f0 + f1 * f1;
    #pragma unroll
    for (int off = 32; off; off >>= 1) {
        sum += __shfl_xor(sum, off);
        sq  += __shfl_xor(sq, off);
    }
    if (lane == 0) {
        float m = sum * (1.0f / 128.0f);
        mu[row]   = m;
        rowq[row] = sq - 128.0f * m * m;   // sum_s rowq = 128*trace(cov) = trc
    }
}

__global__ __launch_bounds__(256)
void trace_red_k(const float* __restrict__ rowq, float* __restrict__ trc)
{
    int b = blockIdx.x, tid = threadIdx.x;
    float v = 0.f;
    for (int s = tid; s < S_; s += 256) v += rowq[(long)b * S_ + s];
    __shared__ float red[256];
    red[tid] = v; __syncthreads();
    if (tid < 128) red[tid] += red[tid + 128];
    __syncthreads();
    if (tid < 64) {
        float r = red[tid] + red[tid + 64];
        #pragma unroll
        for (int off = 32; off; off >>= 1) r += __shfl_xor(r, off);
        if (tid == 0) trc[b] = r;
    }
}

// ---- row softmax (len 432) on split-bf16 logits, one wave/row, out = splits ----
__global__ __launch_bounds__(256)
void softmax_split_k(const ushort_t* __restrict__ ph, const ushort_t* __restrict__ pl,
                     ushort_t* __restrict__ ah, ushort_t* __restrict__ al)
{
    int row  = blockIdx.x * 4 + (threadIdx.x >> 6);
    int lane = threadIdx.x & 63;
    float vals[7];
    float mx = -3.0e38f;
    #pragma unroll
    for (int i = 0; i < 7; ++i) {
        int c = lane + i * 64;
        vals[i] = (c < S_) ? (bf2f(ph[(long)row * S_ + c]) + bf2f(pl[(long)row * S_ + c]))
                           : -3.0e38f;
        mx = fmaxf(mx, vals[i]);
    }
    #pragma unroll
    for (int off = 32; off; off >>= 1) mx = fmaxf(mx, __shfl_xor(mx, off));
    float sum = 0.f;
    #pragma unroll
    for (int i = 0; i < 7; ++i) { vals[i] = __expf(vals[i] - mx); sum += vals[i]; }
    #pragma unroll
    for (int off = 32; off; off >>= 1) sum += __shfl_xor(sum, off);
    float inv = 1.0f / sum;
    #pragma unroll
    for (int i = 0; i < 7; ++i) {
        int c = lane + i * 64;
        if (c < S_) {
            float w = vals[i] * inv;
            ushort_t h, l; split2(w, h, l);
            ah[(long)row * S_ + c] = h;
            al[(long)row * S_ + c] = l;
        }
    }
}

extern "C" void kernel_launch(void* const* d_in, const int* in_sizes, int n_in,
                              void* d_out, int out_size, void* d_ws, size_t ws_size,
                              hipStream_t stream)
{
    (void)in_sizes; (void)n_in; (void)out_size; (void)ws_size;
    const float* x     = (const float*)d_in[0];
    // d_in[1] = mask (all true) -- no-op in the reference math
    const float* Wv    = (const float*)d_in[2];
    const float* bv    = (const float*)d_in[3];
    const float* Wc    = (const float*)d_in[4];
    const float* bc    = (const float*)d_in[5];
    const float* gamma = (const float*)d_in[6];
    const float* beta  = (const float*)d_in[7];
    const float* mean  = (const float*)d_in[8];
    const float* var   = (const float*)d_in[9];
    float* out = (float*)d_out;

    char* p = (char*)d_ws;
    auto alloc = [&](long bytes) { char* r = p; p += (bytes + 255) & ~255L; return r; };

    const long SS  = (long)S_ * S_;        // 186624
    const long SSH = (long)HB * SS;        // chunk S-buffer elems
    const long XSZ = (long)NB * S_ * D_;   // 14155776
    const long FSZ = (long)NB * S_ * C_;
    const long sXD = (long)S_ * D_;
    const long sFC = (long)S_ * C_;

    // x splits live in d_out (exactly fills it; dead before final output write)
    ushort_t* xh = (ushort_t*)d_out;
    ushort_t* xl = xh + XSZ;

    // workspace (~168 MB)
    ushort_t* vTh = (ushort_t*)alloc(XSZ * 2);   // v^T per batch: (D, S)
    ushort_t* vTl = (ushort_t*)alloc(XSZ * 2);
    ushort_t* fth = (ushort_t*)alloc(FSZ * 2);
    ushort_t* ftl = (ushort_t*)alloc(FSZ * 2);
    ushort_t *Sh[4], *Sl[4];
    for (int i = 0; i < 4; ++i) {
        Sh[i] = (ushort_t*)alloc(SSH * 2);
        Sl[i] = (ushort_t*)alloc(SSH * 2);
    }
    ushort_t* Wvh = (ushort_t*)alloc(512L * 512 * 2);
    ushort_t* Wvl = (ushort_t*)alloc(512L * 512 * 2);
    ushort_t* Wch = (ushort_t*)alloc(128L * 512 * 2);
    ushort_t* Wcl = (ushort_t*)alloc(128L * 512 * 2);
    float* mu   = (float*)alloc((long)NB * S_ * 4);
    float* rowq = (float*)alloc((long)NB * S_ * 4);
    float* trc  = (float*)alloc(256);
    float* sc   = (float*)alloc(512);
    float* shv  = (float*)alloc(512);

    const float* nil = nullptr;
    ushort_t* nus = nullptr;
    dim3 blk(256);

    // 0) BN fold + input splits (x splits into d_out)
    bnfold_k<<<1, 128, 0, stream>>>(bc, gamma, beta, mean, var, sc, shv);
    split_k<<<2048, blk, 0, stream>>>(x,  xh,  xl,  XSZ / 4);
    split_k<<<256,  blk, 0, stream>>>(Wv, Wvh, Wvl, (512L * 512) / 4);
    split_k<<<64,   blk, 0, stream>>>(Wc, Wch, Wcl, (128L * 512) / 4);

    // 1) v^T = Wv @ x^T + bv (row bias) -> straight splits, shape (D,S) per batch
    gemm_bf<6, false, true, false><<<dim3(4, 4, NB), blk, 0, stream>>>(
        Wvh, Wvl, xh, xl, vTh, vTl, nus, nus, nullptr,
        D_, S_, D_, D_, D_, S_, 0, sXD, sXD, bv, nil, nil, nil);

    // 2) feat = BN(relu(x)@Wc^T + bc) -> straight splits (S,C)
    gemm_bf<4, true, true, false><<<dim3(4, 1, NB), blk, 0, stream>>>(
        xh, xl, Wch, Wcl, fth, ftl, nus, nus, nullptr,
        S_, C_, D_, D_, D_, C_, sXD, 0, sFC, sc, shv, nil, nil);

    // 3) mu / trace (all batches)
    mu_rowq_bf<<<dim3(NB * S_ / 4), blk, 0, stream>>>(fth, ftl, mu, rowq);
    trace_red_k<<<dim3(NB), blk, 0, stream>>>(rowq, trc);

    // 4) per-chunk: cov -> NS -> logits -> softmax -> attn@v
    for (int cidx = 0; cidx < NB / HB; ++cidx) {
        const long b0 = (long)cidx * HB;
        const ushort_t* fch = fth + b0 * sFC;
        const ushort_t* fcl = ftl + b0 * sFC;
        const float* trcC = trc + b0;
        const float* muC  = mu + b0 * S_;
        dim3 g44(4, 4, HB);

        // cov -> Ah (S0) and ZY0 (S1), both symmetric
        gemm_bf<2, false, false, false><<<g44, blk, 0, stream>>>(
            fch, fcl, fch, fcl, Sh[0], Sl[0], Sh[1], Sl[1], nullptr,
            S_, S_, C_, C_, C_, S_, sFC, sFC, SS, nil, nil, trcC, muC);

        // Newton-Schulz (iterN=5); all operands symmetric -> straight splits both sides
        #define NSG(Fv, AH, AL, BH, BL, CH, CL) \
            gemm_bf<Fv, false, true, false><<<g44, blk, 0, stream>>>( \
                AH, AL, BH, BL, CH, CL, nus, nus, nullptr, \
                S_, S_, S_, S_, S_, S_, SS, SS, SS, nil, nil, nil, nil)

        NSG(0, Sh[0], Sl[0], Sh[1], Sl[1], Sh[2], Sl[2]);  // Y1 = Ah@Z0        -> S2
        NSG(1, Sh[1], Sl[1], Sh[2], Sl[2], Sh[3], Sl[3]);  // T1 = .5(3I-Z0@Y1) -> S3
        NSG(0, Sh[2], Sl[2], Sh[3], Sl[3], Sh[0], Sl[0]);  // Y2 = Y1@T1        -> S0
        NSG(0, Sh[3], Sl[3], Sh[1], Sl[1], Sh[2], Sl[2]);  // Z2 = T1@Z0        -> S2
        NSG(1, Sh[2], Sl[2], Sh[0], Sl[0], Sh[1], Sl[1]);  // T2 = .5(3I-Z2@Y2) -> S1
        NSG(0, Sh[0], Sl[0], Sh[1], Sl[1], Sh[3], Sl[3]);  // Y3 = Y2@T2        -> S3
        NSG(0, Sh[1], Sl[1], Sh[2], Sl[2], Sh[0], Sl[0]);  // Z3 = T2@Z2        -> S0
        NSG(1, Sh[0], Sl[0], Sh[3], Sl[3], Sh[2], Sl[2]);  // T3 = .5(3I-Z3@Y3) -> S2
        NSG(0, Sh[3], Sl[3], Sh[2], Sl[2], Sh[1], Sl[1]);  // Y4 = Y3@T3        -> S1
        NSG(0, Sh[2], Sl[2], Sh[0], Sl[0], Sh[3], Sl[3]);  // Z4 = T3@Z3        -> S3
        NSG(1, Sh[3], Sl[3], Sh[1], Sl[1], Sh[0], Sl[0]);  // T4 = .5(3I-Z4@Y4) -> S0
        #undef NSG

        // logits = (Y4@T4) * sqrt(trc/128)/16 -> splits into S2 (free)
        gemm_bf<5, false, true, false><<<g44, blk, 0, stream>>>(
            Sh[1], Sl[1], Sh[0], Sl[0], Sh[2], Sl[2], nus, nus, nullptr,
            S_, S_, S_, S_, S_, S_, SS, SS, SS, nil, nil, trcC, nil);

        // softmax -> attn splits into S3 (free)
        softmax_split_k<<<dim3(HB * S_ / 4), blk, 0, stream>>>(
            Sh[2], Sl[2], Sh[3], Sl[3]);

        // out = attn @ v  (Bg = v^T splits), fp32 into d_out (x splits dead now)
        gemm_bf<0, false, false, true><<<g44, blk, 0, stream>>>(
            Sh[3], Sl[3], vTh + b0 * sXD, vTl + b0 * sXD, nus, nus, nus, nus,
            out + b0 * sXD,
            S_, D_, S_, S_, S_, D_, SS, sXD, sXD, nil, nil, nil, nil);
    }
}

// Round 6
// 1056.164 us; speedup vs baseline: 1.4435x; 1.4435x over previous
//
#include <hip/hip_runtime.h>
#include <math.h>

#define NB 64
#define S_ 432
#define D_ 512
#define C_ 128

typedef unsigned short ushort_t;
typedef unsigned int uint_t;
typedef __attribute__((ext_vector_type(8))) short short8;
typedef __attribute__((ext_vector_type(4))) float f32x4;

// ---- bf16 helpers (RNE) ----
__device__ inline ushort_t f2bf(float v) {
    uint_t x = __float_as_uint(v);
    x += 0x7fffu + ((x >> 16) & 1u);
    return (ushort_t)(x >> 16);
}
__device__ inline float bf2f(ushort_t b) { return __uint_as_float(((uint_t)b) << 16); }
__device__ inline void split2(float v, ushort_t& h, ushort_t& l) {
    h = f2bf(v);
    l = f2bf(v - bf2f(h));
}
// packed element: (hi<<16)|lo ; value = bf2f(hi)+bf2f(lo)
__device__ inline uint_t pkf(float v) {
    ushort_t h, l; split2(v, h, l);
    return ((uint_t)h << 16) | (uint_t)l;
}
__device__ inline float unpkf(uint_t p) {
    return bf2f((ushort_t)(p >> 16)) + bf2f((ushort_t)(p & 0xffffu));
}

// relu on 8 packed els: sign(value) == bit31 (sign of hi); zero whole el if neg
__device__ inline void relu8(uint4& a, uint4& b) {
    uint_t* p = (uint_t*)&a;
    #pragma unroll
    for (int i = 0; i < 4; ++i) p[i] = ((int)p[i] < 0) ? 0u : p[i];
    p = (uint_t*)&b;
    #pragma unroll
    for (int i = 0; i < 4; ++i) p[i] = ((int)p[i] < 0) ? 0u : p[i];
}

// unpack 8 packed els (p0=els0-3, p1=els4-7) -> 8 hi ushorts (h) + 8 lo (l)
__device__ inline void unpk8(const uint4& p0, const uint4& p1, uint4& h, uint4& l) {
    h.x = (p0.x >> 16) | (p0.y & 0xffff0000u);
    h.y = (p0.z >> 16) | (p0.w & 0xffff0000u);
    h.z = (p1.x >> 16) | (p1.y & 0xffff0000u);
    h.w = (p1.z >> 16) | (p1.w & 0xffff0000u);
    l.x = (p0.x & 0xffffu) | (p0.y << 16);
    l.y = (p0.z & 0xffffu) | (p0.w << 16);
    l.z = (p1.x & 0xffffu) | (p1.y << 16);
    l.w = (p1.z & 0xffffu) | (p1.w << 16);
}

// ---- fp32 -> packed split ----
__global__ __launch_bounds__(256)
void splitp_k(const float* __restrict__ src, uint_t* __restrict__ dst, long n4) {
    long i = (long)blockIdx.x * 256 + threadIdx.x;
    long stride = (long)gridDim.x * 256;
    for (; i < n4; i += stride) {
        float4 v = *(const float4*)&src[i * 4];
        uint4 o;
        o.x = pkf(v.x); o.y = pkf(v.y); o.z = pkf(v.z); o.w = pkf(v.w);
        *(uint4*)&dst[i * 4] = o;
    }
}

// ---------------------------------------------------------------------------
// Packed split-bf16 MFMA GEMM: C[m,n] = epi( sum_k A[m,k] * Bg[n,k] )
// A (M,K) packed, k-contig; Bg (N,K) packed (B^T stored, or B when symmetric).
// acc += Ah*Bh + Ah*Bl + Al*Bh  (3 MFMAs/frag-pair).
// Tile 128x128, 4 waves (2x2), wave = 4x4 frags of 16x16x32 bf16.
// C/D map (m89): col = lane&15, row = (lane>>4)*4 + reg.
// XCD swizzle: xcd = blockIdx.x&7 owns batches z%8==xcd -> same-batch tiles
// share one XCD's L2 (panel reuse). Requires nb%8==0.
// F: 0 none | 1 0.5*(3I-acc) | 2 cov dual-out | 4 *e0[n]+e1[n]
//  | 5 *sqrt(trc/128)/16 | 6 +e0[m]
// WS: packed out to Cp. WF: fp32 out to Cf. F==2: Ah->Cp, ZY0->C2p.
// Edge: m0=min(bx*128,M-128); overlapped blocks write identical bits.
// ---------------------------------------------------------------------------
template<int F, bool RELU, bool WS, bool WF>
__global__ __launch_bounds__(256)
void gemm_pk(const uint_t* __restrict__ Ag, const uint_t* __restrict__ Bg,
             uint_t* __restrict__ Cp, uint_t* __restrict__ C2p,
             float* __restrict__ Cf,
             int M, int N, int K, int lda, int ldb, int ldc,
             long sA, long sB, long sC,
             const float* __restrict__ e0, const float* __restrict__ e1,
             const float* __restrict__ trc, const float* __restrict__ mu,
             int mtl, int tpbl)
{
    __shared__ __align__(16) ushort_t lds4[4][128][40];  // Ah,Al,Bh,Bl; 40 KB

    const int tid = threadIdx.x;
    // XCD-aware decode of 1-D grid
    const int lid = blockIdx.x;
    const int xcd = lid & 7, idx = lid >> 3;
    const int zb = xcd + ((idx >> tpbl) << 3);
    const int t  = idx & ((1 << tpbl) - 1);
    const int bx = t & ((1 << mtl) - 1), by = t >> mtl;
    int m0 = bx << 7; if (m0 > M - 128) m0 = M - 128;
    int n0 = by << 7; if (n0 > N - 128) n0 = N - 128;

    const uint_t* gA = Ag + (long)zb * sA;
    const uint_t* gB = Bg + (long)zb * sB;

    f32x4 acc[4][4];
    #pragma unroll
    for (int i = 0; i < 4; ++i)
        #pragma unroll
        for (int j = 0; j < 4; ++j)
            acc[i][j] = (f32x4){0.f, 0.f, 0.f, 0.f};

    const int srow = tid >> 2;         // 0..63
    const int sq8  = (tid & 3) * 8;    // k el offset: 0,8,16,24
    const int wv = tid >> 6, wr = wv >> 1, wc = wv & 1;
    const int ln = tid & 63, lm = ln & 15, kg = ln >> 4;

    for (int k0 = 0; k0 < K; k0 += 32) {
        const bool kok = (k0 + sq8) < K;   // K%16==0 -> full 8 valid if true
        #pragma unroll
        for (int ps = 0; ps < 2; ++ps) {
            int r = srow + (ps << 6);
            uint4 z4; z4.x = z4.y = z4.z = z4.w = 0u;
            uint4 a0 = z4, a1 = z4, b0 = z4, b1 = z4;
            if (kok) {
                long ao = (long)(m0 + r) * lda + k0 + sq8;
                long bo = (long)(n0 + r) * ldb + k0 + sq8;
                a0 = *(const uint4*)(gA + ao);
                a1 = *(const uint4*)(gA + ao + 4);
                b0 = *(const uint4*)(gB + bo);
                b1 = *(const uint4*)(gB + bo + 4);
            }
            if (RELU) relu8(a0, a1);
            uint4 h, l;
            unpk8(a0, a1, h, l);
            *(uint4*)&lds4[0][r][sq8] = h;
            *(uint4*)&lds4[1][r][sq8] = l;
            unpk8(b0, b1, h, l);
            *(uint4*)&lds4[2][r][sq8] = h;
            *(uint4*)&lds4[3][r][sq8] = l;
        }
        __syncthreads();
        short8 ah[4], al[4], bh[4], bl[4];
        #pragma unroll
        for (int fm = 0; fm < 4; ++fm) {
            ah[fm] = *(const short8*)&lds4[0][wr*64 + fm*16 + lm][kg*8];
            al[fm] = *(const short8*)&lds4[1][wr*64 + fm*16 + lm][kg*8];
        }
        #pragma unroll
        for (int fn = 0; fn < 4; ++fn) {
            bh[fn] = *(const short8*)&lds4[2][wc*64 + fn*16 + lm][kg*8];
            bl[fn] = *(const short8*)&lds4[3][wc*64 + fn*16 + lm][kg*8];
        }
        #pragma unroll
        for (int fm = 0; fm < 4; ++fm)
            #pragma unroll
            for (int fn = 0; fn < 4; ++fn) {
                acc[fm][fn] = __builtin_amdgcn_mfma_f32_16x16x32_bf16(ah[fm], bh[fn], acc[fm][fn], 0, 0, 0);
                acc[fm][fn] = __builtin_amdgcn_mfma_f32_16x16x32_bf16(ah[fm], bl[fn], acc[fm][fn], 0, 0, 0);
                acc[fm][fn] = __builtin_amdgcn_mfma_f32_16x16x32_bf16(al[fm], bh[fn], acc[fm][fn], 0, 0, 0);
            }
        __syncthreads();
    }

    // ---- epilogue ----
    const int rg = kg * 4;
    float fscale = 1.f, invtr = 1.f;
    if (F == 5) fscale = sqrtf(trc[zb] * (1.0f / 128.0f)) * 0.0625f;
    if (F == 2) invtr = 1.0f / trc[zb];

    #pragma unroll
    for (int fm = 0; fm < 4; ++fm) {
        #pragma unroll
        for (int r = 0; r < 4; ++r) {
            int gm = m0 + wr*64 + fm*16 + rg + r;
            float mum = 0.f;
            if (F == 2) mum = mu[(long)zb * S_ + gm];
            #pragma unroll
            for (int fn = 0; fn < 4; ++fn) {
                int gn = n0 + wc*64 + fn*16 + lm;
                float v = acc[fm][fn][r];
                long o = (long)zb * sC + (long)gm * ldc + gn;
                if (F == 2) {
                    float ahv = (v - 128.0f * mum * mu[(long)zb * S_ + gn]) * invtr;
                    Cp[o]  = pkf(ahv);
                    C2p[o] = pkf(((gm == gn) ? 1.5f : 0.0f) - 0.5f * ahv);
                } else {
                    if (F == 1)      v = ((gm == gn) ? 1.5f : 0.0f) - 0.5f * v;
                    else if (F == 4) v = v * e0[gn] + e1[gn];
                    else if (F == 5) v *= fscale;
                    else if (F == 6) v += e0[gm];
                    if (WF) Cf[o] = v;
                    if (WS) Cp[o] = pkf(v);
                }
            }
        }
    }
}

// ---- BN fold: feat = acc*sc[c] + sh[c] ----
__global__ void bnfold_k(const float* __restrict__ bc, const float* __restrict__ gamma,
                         const float* __restrict__ beta, const float* __restrict__ mean,
                         const float* __restrict__ var, float* __restrict__ sc,
                         float* __restrict__ sh)
{
    int c = threadIdx.x;
    float s = gamma[c] / sqrtf(var[c] + 1e-5f);
    sc[c] = s;
    sh[c] = beta[c] + (bc[c] - mean[c]) * s;
}

// ---- per-row channel mean + trace contribution (one wave per feat row) ----
__global__ __launch_bounds__(256)
void mu_rowq_pk(const uint_t* __restrict__ fp, float* __restrict__ mu,
                float* __restrict__ rowq)
{
    int row  = blockIdx.x * 4 + (threadIdx.x >> 6);
    int lane = threadIdx.x & 63;
    uint2 pv = *(const uint2*)&fp[(long)row * C_ + lane * 2];
    float f0 = unpkf(pv.x);
    float f1 = unpkf(pv.y);
    float sum = f0 + f1;
    float sq  = f0 * f0 + f1 * f1;
    #pragma unroll
    for (int off = 32; off; off >>= 1) {
        sum += __shfl_xor(sum, off);
        sq  += __shfl_xor(sq, off);
    }
    if (lane == 0) {
        float m = sum * (1.0f / 128.0f);
        mu[row]   = m;
        rowq[row] = sq - 128.0f * m * m;   // sum_s rowq = 128*trace(cov) = trc
    }
}

__global__ __launch_bounds__(256)
void trace_red_k(const float* __restrict__ rowq, float* __restrict__ trc)
{
    int b = blockIdx.x, tid = threadIdx.x;
    float v = 0.f;
    for (int s = tid; s < S_; s += 256) v += rowq[(long)b * S_ + s];
    __shared__ float red[256];
    red[tid] = v; __syncthreads();
    if (tid < 128) red[tid] += red[tid + 128];
    __syncthreads();
    if (tid < 64) {
        float r = red[tid] + red[tid + 64];
        #pragma unroll
        for (int off = 32; off; off >>= 1) r += __shfl_xor(r, off);
        if (tid == 0) trc[b] = r;
    }
}

// ---- row softmax (len 432) on packed logits, one wave/row, packed out ----
__global__ __launch_bounds__(256)
void softmax_pk(const uint_t* __restrict__ pin, uint_t* __restrict__ pout)
{
    int row  = blockIdx.x * 4 + (threadIdx.x >> 6);
    int lane = threadIdx.x & 63;
    float vals[7];
    float mx = -3.0e38f;
    #pragma unroll
    for (int i = 0; i < 7; ++i) {
        int c = lane + i * 64;
        vals[i] = (c < S_) ? unpkf(pin[(long)row * S_ + c]) : -3.0e38f;
        mx = fmaxf(mx, vals[i]);
    }
    #pragma unroll
    for (int off = 32; off; off >>= 1) mx = fmaxf(mx, __shfl_xor(mx, off));
    float sum = 0.f;
    #pragma unroll
    for (int i = 0; i < 7; ++i) { vals[i] = __expf(vals[i] - mx); sum += vals[i]; }
    #pragma unroll
    for (int off = 32; off; off >>= 1) sum += __shfl_xor(sum, off);
    float inv = 1.0f / sum;
    #pragma unroll
    for (int i = 0; i < 7; ++i) {
        int c = lane + i * 64;
        if (c < S_) pout[(long)row * S_ + c] = pkf(vals[i] * inv);
    }
}

extern "C" void kernel_launch(void* const* d_in, const int* in_sizes, int n_in,
                              void* d_out, int out_size, void* d_ws, size_t ws_size,
                              hipStream_t stream)
{
    (void)in_sizes; (void)n_in; (void)out_size;
    const float* x     = (const float*)d_in[0];
    // d_in[1] = mask (all true) -- no-op in the reference math
    const float* Wv    = (const float*)d_in[2];
    const float* bv    = (const float*)d_in[3];
    const float* Wc    = (const float*)d_in[4];
    const float* bc    = (const float*)d_in[5];
    const float* gamma = (const float*)d_in[6];
    const float* beta  = (const float*)d_in[7];
    const float* mean  = (const float*)d_in[8];
    const float* var   = (const float*)d_in[9];
    float* out = (float*)d_out;

    const long SS  = (long)S_ * S_;        // 186624
    const long XSZ = (long)NB * S_ * D_;   // 14155776
    const long FSZ = (long)NB * S_ * C_;
    const long sXD = (long)S_ * D_;
    const long sFC = (long)S_ * C_;

    // adaptive chunk size: 64 batches if workspace allows, else 32
    const long need64 = XSZ*4L + FSZ*4L + 4L*64*SS*4 + (1L<<20) + (1L<<18)
                      + (long)NB*S_*8 + 16384;
    const int HBr = (ws_size >= (size_t)need64) ? 64 : 32;

    char* p = (char*)d_ws;
    auto alloc = [&](long bytes) { char* r = p; p += (bytes + 255) & ~255L; return r; };

    // x packed lives in d_out (exact fit; dead before final output writes)
    uint_t* xp = (uint_t*)d_out;

    uint_t* vTp = (uint_t*)alloc(XSZ * 4);   // v^T per batch: (D,S) packed
    uint_t* ftp = (uint_t*)alloc(FSZ * 4);   // feat (S,C) packed
    uint_t* Sp[4];
    for (int i = 0; i < 4; ++i) Sp[i] = (uint_t*)alloc((long)HBr * SS * 4);
    uint_t* Wvp = (uint_t*)alloc(512L * 512 * 4);
    uint_t* Wcp = (uint_t*)alloc(128L * 512 * 4);
    float* mu   = (float*)alloc((long)NB * S_ * 4);
    float* rowq = (float*)alloc((long)NB * S_ * 4);
    float* trc  = (float*)alloc(256);
    float* sc   = (float*)alloc(512);
    float* shv  = (float*)alloc(512);

    const float* nil = nullptr;
    uint_t* nup = nullptr;
    dim3 blk(256);

    // 0) BN fold + packed input splits (x into d_out)
    bnfold_k<<<1, 128, 0, stream>>>(bc, gamma, beta, mean, var, sc, shv);
    splitp_k<<<2048, blk, 0, stream>>>(x,  xp,  XSZ / 4);
    splitp_k<<<256,  blk, 0, stream>>>(Wv, Wvp, (512L * 512) / 4);
    splitp_k<<<64,   blk, 0, stream>>>(Wc, Wcp, (128L * 512) / 4);

    // 1) v^T = Wv @ x^T + bv (row bias): M=D,N=S,K=D ; 16 tiles/batch
    gemm_pk<6, false, true, false><<<dim3(16 * NB), blk, 0, stream>>>(
        Wvp, xp, vTp, nup, nullptr,
        D_, S_, D_, D_, D_, S_, 0, sXD, sXD, bv, nil, nil, nil, 2, 4);

    // 2) feat = BN(relu(x)@Wc^T + bc): M=S,N=C,K=D ; 4 tiles/batch
    gemm_pk<4, true, true, false><<<dim3(4 * NB), blk, 0, stream>>>(
        xp, Wcp, ftp, nup, nullptr,
        S_, C_, D_, D_, D_, C_, sXD, 0, sFC, sc, shv, nil, nil, 2, 2);

    // 3) mu / trace (all batches)
    mu_rowq_pk<<<dim3(NB * S_ / 4), blk, 0, stream>>>(ftp, mu, rowq);
    trace_red_k<<<dim3(NB), blk, 0, stream>>>(rowq, trc);

    // 4) per-chunk: cov -> NS -> logits -> softmax -> attn@v
    for (int b0 = 0; b0 < NB; b0 += HBr) {
        const uint_t* fc = ftp + (long)b0 * sFC;
        const float* trcC = trc + b0;
        const float* muC  = mu + (long)b0 * S_;
        dim3 gS(16 * HBr);

        // cov -> Ah (S0) and ZY0 (S1), both symmetric
        gemm_pk<2, false, false, false><<<gS, blk, 0, stream>>>(
            fc, fc, Sp[0], Sp[1], nullptr,
            S_, S_, C_, C_, C_, S_, sFC, sFC, SS, nil, nil, trcC, muC, 2, 4);

        // Newton-Schulz (iterN=5); symmetric operands -> packed both sides
        #define NSG(Fv, PA, PB, PC) \
            gemm_pk<Fv, false, true, false><<<gS, blk, 0, stream>>>( \
                PA, PB, PC, nup, nullptr, \
                S_, S_, S_, S_, S_, S_, SS, SS, SS, nil, nil, nil, nil, 2, 4)

        NSG(0, Sp[0], Sp[1], Sp[2]);  // Y1 = Ah@Z0        -> S2
        NSG(1, Sp[1], Sp[2], Sp[3]);  // T1 = .5(3I-Z0@Y1) -> S3
        NSG(0, Sp[2], Sp[3], Sp[0]);  // Y2 = Y1@T1        -> S0
        NSG(0, Sp[3], Sp[1], Sp[2]);  // Z2 = T1@Z0        -> S2
        NSG(1, Sp[2], Sp[0], Sp[1]);  // T2 = .5(3I-Z2@Y2) -> S1
        NSG(0, Sp[0], Sp[1], Sp[3]);  // Y3 = Y2@T2        -> S3
        NSG(0, Sp[1], Sp[2], Sp[0]);  // Z3 = T2@Z2        -> S0
        NSG(1, Sp[0], Sp[3], Sp[2]);  // T3 = .5(3I-Z3@Y3) -> S2
        NSG(0, Sp[3], Sp[2], Sp[1]);  // Y4 = Y3@T3        -> S1
        NSG(0, Sp[2], Sp[0], Sp[3]);  // Z4 = T3@Z3        -> S3
        NSG(1, Sp[3], Sp[1], Sp[0]);  // T4 = .5(3I-Z4@Y4) -> S0
        #undef NSG

        // logits = (Y4@T4) * sqrt(trc/128)/16 -> packed into S2
        gemm_pk<5, false, true, false><<<gS, blk, 0, stream>>>(
            Sp[1], Sp[0], Sp[2], nup, nullptr,
            S_, S_, S_, S_, S_, S_, SS, SS, SS, nil, nil, trcC, nil, 2, 4);

        // softmax -> packed attn into S3
        softmax_pk<<<dim3(HBr * S_ / 4), blk, 0, stream>>>(Sp[2], Sp[3]);

        // out = attn @ v (Bg = v^T packed), fp32 into d_out (xp dead now)
        gemm_pk<0, false, false, true><<<gS, blk, 0, stream>>>(
            Sp[3], vTp + (long)b0 * sXD, nup, nup, out + (long)b0 * sXD,
            S_, D_, S_, S_, S_, D_, SS, sXD, sXD, nil, nil, nil, nil, 2, 4);
    }
}